// Round 2
// baseline (8399.485 us; speedup 1.0000x reference)
//
#include <hip/hip_runtime.h>
#include <math.h>

#define BB 128
#define TT 512
#define FF 128
#define HH 512
#define NR 2048      // gate rows, row = 4*j + g
#define HB (HH*BB)   // 65536 elements per h state
#define FLS 16       // flag stride (ints): one flag per 64B line

typedef __attribute__((ext_vector_type(8))) short short8;   // 8 bf16
typedef __attribute__((ext_vector_type(4))) float f32x4;    // MFMA C/D frag
typedef unsigned int uint;
typedef unsigned short ushort;
typedef unsigned long long u64;

#define MFMA __builtin_amdgcn_mfma_f32_16x16x32_bf16
#define AT_LD(p)   __hip_atomic_load((p), __ATOMIC_RELAXED, __HIP_MEMORY_SCOPE_AGENT)
#define AT_ST(p,v) __hip_atomic_store((p), (v), __ATOMIC_RELAXED, __HIP_MEMORY_SCOPE_AGENT)

__device__ __forceinline__ ushort f2bf(float f) {           // fp32 -> bf16 RNE
  uint u = __float_as_uint(f);
  u += 0x7fff + ((u >> 16) & 1);
  return (ushort)(u >> 16);
}
__device__ __forceinline__ float bfh(ushort h) { return __uint_as_float(((uint)h) << 16); }
// 2-byte device-coherent (write-through) store: 16-bit __hip_atomic_store may
// CAS-expand, so emit the native instruction directly.
__device__ __forceinline__ void st2_wt(ushort* p, uint v) {
  asm volatile("global_store_short %0, %1, off sc0 sc1" :: "v"(p), "v"(v) : "memory");
}
__device__ __forceinline__ u64 pk2f(float a, float b) {
  return ((u64)__float_as_uint(b) << 32) | (u64)__float_as_uint(a);
}

// ---------------- prep kernels ----------------

__global__ __launch_bounds__(256) void k_zero(float* __restrict__ p, int n) {
  int i = blockIdx.x * 256 + threadIdx.x;
  if (i < n) p[i] = 0.f;
}

// bias [2048] (col = g*512 + j) -> bp[j*4+g]
__global__ __launch_bounds__(256) void k_rearr_b(const float* __restrict__ src,
                                                 float* __restrict__ dst) {
  int idx = blockIdx.x * 256 + threadIdx.x;   // 2048
  int j = idx & 511, g = idx >> 9;
  dst[j * 4 + g] = src[idx];
}

// [K][2048] matrix -> A-fragment order, bf16 hi/lo split. KT=1<<ktsh k-tiles.
// dst[((jb*KT + kt)*64 + L)*16 + term*8 + j8]:
//   k = kt*32 + (L>>4)*8 + j8 ; m = L&15 ; j = jb*4 + (m>>2) ; g = m&3
__global__ __launch_bounds__(256) void k_pack_A(const float* __restrict__ src,
                                                ushort* __restrict__ dst, int ktsh) {
  int idx = blockIdx.x * 256 + threadIdx.x;
  int KTm1 = (1 << ktsh) - 1;
  int j8 = idx & 7;
  int L = (idx >> 3) & 63;
  int kt = (idx >> 9) & KTm1;
  int jb = idx >> (9 + ktsh);
  int k = kt * 32 + (L >> 4) * 8 + j8;
  int m = L & 15;
  int j = jb * 4 + (m >> 2);
  int g = m & 3;
  float v = src[(size_t)k * NR + g * HH + j];
  ushort hi = f2bf(v);
  ushort lo = f2bf(v - bfh(hi));
  size_t base = ((size_t)((jb << ktsh) + kt) * 64 + L) * 16;
  dst[base + j8] = hi;
  dst[base + 8 + j8] = lo;
}

// ---------------- fused persistent 2-layer LSTM, specialized blocks ----------
// 256 blocks x 256 thr (1/CU). Blocks 0..127 = REC (recurrence only), blocks
// 128..255 = PROJ (input projections W*x(t) / W2*h1(t) into a 4-slot xz ring,
// throttled <=4 steps ahead of partner rec block via flags).
// Rec block b: ch=b&3 (col group, 32 cols at ch*32), jb2=b>>2 (16 hidden units
// at jb2*16). 4 waves: wave w = (rt-pair w&1, col-tile w>>1); each wave holds
// U A-frags for 2 row-tiles resident (256 VGPR) and computes 96 MFMA/step.
// h is stored as bf16 hi/lo PLANES, col-major [col][j], via write-through 2B
// stores -> consumers load contiguous 16B short8 B-frags with NO split VALU.
// Phase A (h1 chain in seq planes): write-once addresses -> plain cached
// loads (R1-proven freshness); ch-group lives on 2 XCDs (bid%8 round-robin)
// so lines are L2-shared. Phase B (h2 in 4-slot ring planes): addresses
// reused -> 8B agent-atomic loads (L1/L2 bypass, natively lowered).
// Flag protocol as proven: write-through stores drained by __syncthreads,
// then one relaxed atomic flag store; consumers poll relaxed atomic loads +
// compiler barrier. Global step G = 0..1023 (phase switch at G==512).
__global__ __launch_bounds__(256, 1) void k_fused(
    const float* __restrict__ x,
    const ushort* __restrict__ W1pk, const ushort* __restrict__ U1pk,
    const float* __restrict__ bp1,
    const ushort* __restrict__ W2pk, const ushort* __restrict__ U2pk,
    const float* __restrict__ bp2,
    ushort* __restrict__ shi, ushort* __restrict__ slo,   // seq planes [512][col][j]
    ushort* __restrict__ rhi, ushort* __restrict__ rlo,   // ring planes [4][col][j]
    float4* __restrict__ xzr,                             // [4][j*BB+col] gates f4
    int* __restrict__ hflags, int* __restrict__ pflags) {
  int tid = threadIdx.x;
  int L = tid & 63;
  int w = tid >> 6;
  int q = L >> 4, n = L & 15;
  int rtp = w & 1, ctw = w >> 1;
  bool isrec = (blockIdx.x < 128);
  int b = isrec ? blockIdx.x : (blockIdx.x - 128);
  int ch = b & 3, jb2 = b >> 2;
  int col = ch * 32 + ctw * 16 + n;
  int jbp0 = jb2 * 4 + rtp * 2;      // row tiles jbp0, jbp0+1
  int j0 = jbp0 * 4 + q;             // units j0, j0+4

  if (isrec) {
    short8 uh[2][16], ul[2][16];
    auto loadU = [&](const ushort* Up) {
#pragma unroll
      for (int r = 0; r < 2; ++r)
#pragma unroll
        for (int kt = 0; kt < 16; ++kt) {
          const ushort* p = Up + (((size_t)(jbp0 + r) * 16 + kt) * 64 + L) * 16;
          uh[r][kt] = *(const short8*)(p);
          ul[r][kt] = *(const short8*)(p + 8);
        }
    };
    loadU(U1pk);
    float4 bv[2];
    bv[0] = *(const float4*)(bp1 + j0 * 4);
    bv[1] = *(const float4*)(bp1 + (j0 + 4) * 4);
    float c_reg[2] = {0.f, 0.f};
    int fidx = ((L & 31) * 4 + ch) * FLS;

#pragma unroll 1
    for (int G = 0; G < 2 * TT; ++G) {
      if (G == TT) {    // layer 2: swap U, bias; c2_0 = c1_T carries in c_reg
        loadU(U2pk);
        bv[0] = *(const float4*)(bp2 + j0 * 4);
        bv[1] = *(const float4*)(bp2 + (j0 + 4) * 4);
      }
      // poll: h(G-1) ready (group flags >= G) and xz(G) ready (pflag >= G+1)
      while (true) {
        int hf = AT_LD(hflags + fidx);
        int pf = AT_LD(pflags + b * FLS);
        if (__all((hf >= G) && (pf >= G + 1))) break;
      }
      asm volatile("" ::: "memory");
      // xz for this step (4-slot ring, bypass loads)
      float xzv[2][4];
#pragma unroll
      for (int r = 0; r < 2; ++r) {
        const u64* xp = (const u64*)(xzr + ((size_t)(G & 3) * HB + (j0 + 4 * r) * BB + col));
        u64 a = AT_LD(xp), bq = AT_LD(xp + 1);
        xzv[r][0] = __uint_as_float((uint)a);
        xzv[r][1] = __uint_as_float((uint)(a >> 32));
        xzv[r][2] = __uint_as_float((uint)bq);
        xzv[r][3] = __uint_as_float((uint)(bq >> 32));
      }
      f32x4 A0[2], A1[2], A2[2];
#pragma unroll
      for (int r = 0; r < 2; ++r) {
        A0[r] = (f32x4){0.f, 0.f, 0.f, 0.f}; A1[r] = A0[r]; A2[r] = A0[r];
      }
      if (G != 0) {
        if (G < TT) {
          // phase A: plain cached short8 loads from seq planes (write-once)
          const ushort* ph = shi + (size_t)(G - 1) * HB + (size_t)col * HH + q * 8;
          const ushort* pl = slo + (size_t)(G - 1) * HB + (size_t)col * HH + q * 8;
#pragma unroll
          for (int kh = 0; kh < 2; ++kh) {
            short8 bh[8], bl[8];
#pragma unroll
            for (int k8 = 0; k8 < 8; ++k8) {
              bh[k8] = *(const short8*)(ph + (kh * 8 + k8) * 32);
              bl[k8] = *(const short8*)(pl + (kh * 8 + k8) * 32);
            }
#pragma unroll
            for (int k8 = 0; k8 < 8; ++k8) {
              int kt = kh * 8 + k8;
#pragma unroll
              for (int r = 0; r < 2; ++r) {
                A0[r] = MFMA(uh[r][kt], bh[k8], A0[r], 0, 0, 0);
                A1[r] = MFMA(ul[r][kt], bh[k8], A1[r], 0, 0, 0);
                A2[r] = MFMA(uh[r][kt], bl[k8], A2[r], 0, 0, 0);
              }
            }
          }
        } else {
          // phase B: ring planes, 8B agent-atomic (bypass) loads
          size_t rb = (size_t)((G - 1) & 3) * HB + (size_t)col * HH + q * 8;
          const u64* ph = (const u64*)(rhi + rb);
          const u64* pl = (const u64*)(rlo + rb);
#pragma unroll
          for (int kh = 0; kh < 2; ++kh) {
            short8 bh[8], bl[8];
#pragma unroll
            for (int k8 = 0; k8 < 8; ++k8) {
              int kt = kh * 8 + k8;
              union { short8 v; u64 u[2]; } fh, fl;
              fh.u[0] = AT_LD(ph + kt * 8); fh.u[1] = AT_LD(ph + kt * 8 + 1);
              fl.u[0] = AT_LD(pl + kt * 8); fl.u[1] = AT_LD(pl + kt * 8 + 1);
              bh[k8] = fh.v; bl[k8] = fl.v;
            }
#pragma unroll
            for (int k8 = 0; k8 < 8; ++k8) {
              int kt = kh * 8 + k8;
#pragma unroll
              for (int r = 0; r < 2; ++r) {
                A0[r] = MFMA(uh[r][kt], bh[k8], A0[r], 0, 0, 0);
                A1[r] = MFMA(ul[r][kt], bh[k8], A1[r], 0, 0, 0);
                A2[r] = MFMA(uh[r][kt], bl[k8], A2[r], 0, 0, 0);
              }
            }
          }
        }
      }
      // activations + h store (planes, write-through 2B)
#pragma unroll
      for (int r = 0; r < 2; ++r) {
        float z0 = A0[r].x + A1[r].x + A2[r].x + xzv[r][0];
        float z1 = A0[r].y + A1[r].y + A2[r].y + xzv[r][1];
        float z2 = A0[r].z + A1[r].z + A2[r].z + xzv[r][2];
        float z3 = A0[r].w + A1[r].w + A2[r].w + xzv[r][3];
        float ig = 1.f / (1.f + __expf(-z0));
        float fg = 1.f / (1.f + __expf(-z1));
        float gg = tanhf(z2);
        float og = 1.f / (1.f + __expf(-z3));
        c_reg[r] = fg * c_reg[r] + ig * gg;
        float hn = og * tanhf(c_reg[r]);
        ushort hh = f2bf(hn);
        ushort hl = f2bf(hn - bfh(hh));
        size_t off = (size_t)col * HH + (j0 + 4 * r);
        if (G < TT) {
          st2_wt(shi + (size_t)G * HB + off, hh);
          st2_wt(slo + (size_t)G * HB + off, hl);
        }
        if (G >= TT - 1) {   // G==511 seeds h2(-1) into slot 3; phase B: slot G&3
          st2_wt(rhi + (size_t)(G & 3) * HB + off, hh);
          st2_wt(rlo + (size_t)(G & 3) * HB + off, hl);
        }
      }
      __syncthreads();   // drain write-through stores of all 4 waves
      if (tid == 0) AT_ST(hflags + b * FLS, G + 1);
    }
  } else {
    // ---------------- PROJ block ----------------
    short8 w1h[2][4], w1l[2][4];
#pragma unroll
    for (int r = 0; r < 2; ++r)
#pragma unroll
      for (int kt = 0; kt < 4; ++kt) {
        const ushort* p = W1pk + (((size_t)(jbp0 + r) * 4 + kt) * 64 + L) * 16;
        w1h[r][kt] = *(const short8*)(p);
        w1l[r][kt] = *(const short8*)(p + 8);
      }
    float4 bv[2];
    bv[0] = *(const float4*)(bp1 + j0 * 4);
    bv[1] = *(const float4*)(bp1 + (j0 + 4) * 4);

#pragma unroll 1
    for (int G = 0; G < 2 * TT; ++G) {
      if (G == TT) {
        bv[0] = *(const float4*)(bp2 + j0 * 4);
        bv[1] = *(const float4*)(bp2 + (j0 + 4) * 4);
      }
      // throttle: slot G&3 last consumed by partner at step G-4 -> flag >= G-3
      if (G >= 4) {
        while (AT_LD(hflags + b * FLS) < G - 3) {}
      }
      asm volatile("" ::: "memory");
      f32x4 P0[2], P1[2], P2[2];
#pragma unroll
      for (int r = 0; r < 2; ++r) {
        P0[r] = (f32x4){0.f, 0.f, 0.f, 0.f}; P1[r] = P0[r]; P2[r] = P0[r];
      }
      if (G < TT) {
        // xz1(G) = W1 * x(G): split x on the fly (proj blocks have slack)
        const float* xp = x + ((size_t)col * TT + G) * FF + q * 8;
#pragma unroll
        for (int kt = 0; kt < 4; ++kt) {
          float4 v0 = *(const float4*)(xp + kt * 32);
          float4 v1 = *(const float4*)(xp + kt * 32 + 4);
          float xf[8] = {v0.x, v0.y, v0.z, v0.w, v1.x, v1.y, v1.z, v1.w};
          short8 xh, xl;
#pragma unroll
          for (int u = 0; u < 8; ++u) {
            ushort hi = f2bf(xf[u]);
            xl[u] = (short)f2bf(xf[u] - bfh(hi));
            xh[u] = (short)hi;
          }
#pragma unroll
          for (int r = 0; r < 2; ++r) {
            P0[r] = MFMA(w1h[r][kt], xh, P0[r], 0, 0, 0);
            P1[r] = MFMA(w1l[r][kt], xh, P1[r], 0, 0, 0);
            P2[r] = MFMA(w1h[r][kt], xl, P2[r], 0, 0, 0);
          }
        }
      } else {
        // xz2(sp) = W2 * h1(sp): seq planes plain (final, L2-hot), W2 streamed
        int sp = G - TT;
        const ushort* ph = shi + (size_t)sp * HB + (size_t)col * HH + q * 8;
        const ushort* pl = slo + (size_t)sp * HB + (size_t)col * HH + q * 8;
#pragma unroll
        for (int kt = 0; kt < 16; ++kt) {
          short8 bh = *(const short8*)(ph + kt * 32);
          short8 bl = *(const short8*)(pl + kt * 32);
#pragma unroll
          for (int r = 0; r < 2; ++r) {
            const ushort* ab = W2pk + (((size_t)(jbp0 + r) * 16 + kt) * 64 + L) * 16;
            short8 ah = *(const short8*)(ab);
            short8 al = *(const short8*)(ab + 8);
            P0[r] = MFMA(ah, bh, P0[r], 0, 0, 0);
            P1[r] = MFMA(al, bh, P1[r], 0, 0, 0);
            P2[r] = MFMA(ah, bl, P2[r], 0, 0, 0);
          }
        }
      }
      // store gates float4 -> xz ring (write-through 8B atomics)
#pragma unroll
      for (int r = 0; r < 2; ++r) {
        float o0 = P0[r].x + P1[r].x + P2[r].x + bv[r].x;
        float o1 = P0[r].y + P1[r].y + P2[r].y + bv[r].y;
        float o2 = P0[r].z + P1[r].z + P2[r].z + bv[r].z;
        float o3 = P0[r].w + P1[r].w + P2[r].w + bv[r].w;
        u64* dp = (u64*)(xzr + ((size_t)(G & 3) * HB + (j0 + 4 * r) * BB + col));
        AT_ST(dp, pk2f(o0, o1));
        AT_ST(dp + 1, pk2f(o2, o3));
      }
      __syncthreads();
      if (tid == 0) AT_ST(pflags + b * FLS, G + 1);
    }
  }
}

// ---------------- dense + softmax (reads ring slot 3 planes) ----------------
__global__ __launch_bounds__(64) void k_dense(const ushort* __restrict__ rhi,
                                              const ushort* __restrict__ rlo,
                                              const float* __restrict__ Wd,
                                              const float* __restrict__ bd,
                                              float* __restrict__ out) {
  int b = blockIdx.x * 64 + threadIdx.x;
  float acc[10];
#pragma unroll
  for (int c = 0; c < 10; ++c) acc[c] = bd[c];
  const ushort* ph = rhi + (size_t)3 * HB + (size_t)b * HH;
  const ushort* pl = rlo + (size_t)3 * HB + (size_t)b * HH;
  for (int k = 0; k < HH; ++k) {
    float hv = bfh(ph[k]) + bfh(pl[k]);
#pragma unroll
    for (int c = 0; c < 10; ++c) acc[c] = fmaf(hv, Wd[k * 10 + c], acc[c]);
  }
  float m = acc[0];
#pragma unroll
  for (int c = 1; c < 10; ++c) m = fmaxf(m, acc[c]);
  float s = 0.f;
#pragma unroll
  for (int c = 0; c < 10; ++c) { acc[c] = __expf(acc[c] - m); s += acc[c]; }
  float inv = 1.f / s;
#pragma unroll
  for (int c = 0; c < 10; ++c) out[b * 10 + c] = acc[c] * inv;
}

// ---------------- host ----------------
extern "C" void kernel_launch(void* const* d_in, const int* in_sizes, int n_in,
                              void* d_out, int out_size, void* d_ws, size_t ws_size,
                              hipStream_t stream) {
  const float* x  = (const float*)d_in[0];
  const float* W1 = (const float*)d_in[1];
  const float* U1 = (const float*)d_in[2];
  const float* b1 = (const float*)d_in[3];
  const float* W2 = (const float*)d_in[4];
  const float* U2 = (const float*)d_in[5];
  const float* b2 = (const float*)d_in[6];
  const float* Wd = (const float*)d_in[7];
  const float* bd = (const float*)d_in[8];
  float* out = (float*)d_out;

  // workspace layout (~153 MB total, < proven 181 MB)
  ushort* shi   = (ushort*)d_ws;                    // 33,554,432 ush (64 MB)
  ushort* slo   = shi + (size_t)TT * HB;            // 64 MB
  ushort* rhi   = slo + (size_t)TT * HB;            // 4*HB ush
  ushort* rlo   = rhi + (size_t)4 * HB;             // 4*HB ush
  float4* xzr   = (float4*)(rlo + (size_t)4 * HB);  // 4*HB float4 (4 MB)
  ushort* W1pk  = (ushort*)(xzr + (size_t)4 * HB);  //   524,288 ush
  ushort* U1pk  = W1pk + (size_t)524288;            // 2,097,152 ush
  ushort* U2pk  = U1pk + (size_t)2097152;           // 2,097,152 ush
  ushort* W2pk  = U2pk + (size_t)2097152;           // 2,097,152 ush
  float*  bp1   = (float*)(W2pk + (size_t)2097152); // 2,048 f
  float*  bp2   = bp1 + NR;                         // 2,048 f
  int*    hflags = (int*)(bp2 + NR);                // 128*FLS ints
  int*    pflags = hflags + 128 * FLS;              // 128*FLS ints

  k_zero<<<16, 256, 0, stream>>>((float*)hflags, 2 * 128 * FLS);
  k_rearr_b<<<8, 256, 0, stream>>>(b1, bp1);
  k_rearr_b<<<8, 256, 0, stream>>>(b2, bp2);
  k_pack_A<<<1024, 256, 0, stream>>>(W1, W1pk, 2);   // K=128 -> 4 k-tiles
  k_pack_A<<<4096, 256, 0, stream>>>(U1, U1pk, 4);   // K=512 -> 16 k-tiles
  k_pack_A<<<4096, 256, 0, stream>>>(U2, U2pk, 4);
  k_pack_A<<<4096, 256, 0, stream>>>(W2, W2pk, 4);

  k_fused<<<256, 256, 0, stream>>>(x, W1pk, U1pk, bp1, W2pk, U2pk, bp2,
                                   shi, slo, rhi, rlo, xzr, hflags, pflags);
  k_dense<<<2, 64, 0, stream>>>(rhi, rlo, Wd, bd, out);
}

// Round 3
// 6375.721 us; speedup vs baseline: 1.3174x; 1.3174x over previous
//
#include <hip/hip_runtime.h>
#include <math.h>

#define BB 128
#define TT 512
#define FF 128
#define HH 512
#define NR 2048      // gate rows, row = 4*j + g
#define HB (HH*BB)   // 65536 words per h state
#define FLS 16       // flag stride (ints): one flag per 64B line

typedef __attribute__((ext_vector_type(8))) short short8;   // 8 bf16
typedef __attribute__((ext_vector_type(4))) float f32x4;    // MFMA C/D frag
typedef unsigned int uint;
typedef unsigned short ushort;
typedef unsigned long long u64;

#define MFMA __builtin_amdgcn_mfma_f32_16x16x32_bf16
#define AT_LD(p)   __hip_atomic_load((p), __ATOMIC_RELAXED, __HIP_MEMORY_SCOPE_AGENT)
#define AT_ST(p,v) __hip_atomic_store((p), (v), __ATOMIC_RELAXED, __HIP_MEMORY_SCOPE_AGENT)

__device__ __forceinline__ ushort f2bf(float f) {           // fp32 -> bf16 RNE
  uint u = __float_as_uint(f);
  u += 0x7fff + ((u >> 16) & 1);
  return (ushort)(u >> 16);
}
__device__ __forceinline__ float bfh(ushort h) { return __uint_as_float(((uint)h) << 16); }
__device__ __forceinline__ u64 pk2f(float a, float b) {
  return ((u64)__float_as_uint(b) << 32) | (u64)__float_as_uint(a);
}
// 8 packed words (hi16|lo16) -> hi/lo short8 B-frags via v_perm (1 op/dword)
__device__ __forceinline__ void split8(const uint* w, short8& bh, short8& bl) {
  union { short8 v; uint d[4]; } H, Lo;
#pragma unroll
  for (int d = 0; d < 4; ++d) {
    H.d[d]  = __builtin_amdgcn_perm(w[2 * d + 1], w[2 * d], 0x07060302u);
    Lo.d[d] = __builtin_amdgcn_perm(w[2 * d + 1], w[2 * d], 0x05040100u);
  }
  bh = H.v; bl = Lo.v;
}

// ---------------- prep kernels ----------------

__global__ __launch_bounds__(256) void k_zero(float* __restrict__ p, int n) {
  int i = blockIdx.x * 256 + threadIdx.x;
  if (i < n) p[i] = 0.f;
}

// bias [2048] (col = g*512 + j) -> bp[j*4+g]
__global__ __launch_bounds__(256) void k_rearr_b(const float* __restrict__ src,
                                                 float* __restrict__ dst) {
  int idx = blockIdx.x * 256 + threadIdx.x;   // 2048
  int j = idx & 511, g = idx >> 9;
  dst[j * 4 + g] = src[idx];
}

// [K][2048] matrix -> A-fragment order, bf16 hi/lo split. KT=1<<ktsh k-tiles.
// dst[((jb*KT + kt)*64 + L)*16 + term*8 + j8]:
//   k = kt*32 + (L>>4)*8 + j8 ; m = L&15 ; j = jb*4 + (m>>2) ; g = m&3
__global__ __launch_bounds__(256) void k_pack_A(const float* __restrict__ src,
                                                ushort* __restrict__ dst, int ktsh) {
  int idx = blockIdx.x * 256 + threadIdx.x;
  int KTm1 = (1 << ktsh) - 1;
  int j8 = idx & 7;
  int L = (idx >> 3) & 63;
  int kt = (idx >> 9) & KTm1;
  int jb = idx >> (9 + ktsh);
  int k = kt * 32 + (L >> 4) * 8 + j8;
  int m = L & 15;
  int j = jb * 4 + (m >> 2);
  int g = m & 3;
  float v = src[(size_t)k * NR + g * HH + j];
  ushort hi = f2bf(v);
  ushort lo = f2bf(v - bfh(hi));
  size_t base = ((size_t)((jb << ktsh) + kt) * 64 + L) * 16;
  dst[base + j8] = hi;
  dst[base + 8 + j8] = lo;
}

// ---------------- fused persistent 2-layer LSTM, specialized blocks ----------
// 256 blocks x 256 thr (1/CU). Blocks 0..127 REC, 128..255 PROJ (partner b).
// Block b: ch=b&3 (32 cols at ch*32), jb4=b>>2 (16 units at jb4*16). Wave w
// owns row-tile jbp=jb4*4+w (4 units), both col-tiles (ct=0,1) -> 96 MFMA/step.
// ALL data layouts are R1-proven: h = packed hi|lo uint at [j*BB+col], 4B
// agent-atomic coalesced stores; seq write-once -> plain cached loads; ring
// (reused addrs) -> 4B atomic loads; xz ring -> 8B atomic ld/st. Flags: rec
// sets hflags[b]=G+1 after syncthreads-drained stores; rec polls its 32-block
// ch-group (lane L -> block (L&31)*4+ch) AND partner pflag>=G+1; proj
// throttles on partner hflag >= G-3 (4-slot rings). Deadlock-free: proj
// depends only on a lagging flag; ring overwrites are >=2 steps behind all
// group readers by the group poll.
__global__ __launch_bounds__(256, 1) void k_fused(
    const float* __restrict__ x,
    const ushort* __restrict__ W1pk, const ushort* __restrict__ U1pk,
    const float* __restrict__ bp1,
    const ushort* __restrict__ W2pk, const ushort* __restrict__ U2pk,
    const float* __restrict__ bp2,
    uint* __restrict__ seq, uint* __restrict__ ring,
    float4* __restrict__ xzr,
    int* __restrict__ hflags, int* __restrict__ pflags) {
  int tid = threadIdx.x;
  int L = tid & 63;
  int w = tid >> 6;
  int q = L >> 4, n = L & 15;
  bool isrec = (blockIdx.x < 128);
  int b = isrec ? blockIdx.x : (blockIdx.x - 128);
  int ch = b & 3, jb4 = b >> 2;
  int jbp = jb4 * 4 + w;          // this wave's row tile
  int j = jbp * 4 + q;            // this lane's hidden unit
  int col0 = ch * 32 + n;         // + ct*16
  int pidx = b * FLS;

  short8 uh[16], ul[16];          // resident A-frags (1 row-tile = 128 VGPR)

  if (isrec) {
#pragma unroll
    for (int kt = 0; kt < 16; ++kt) {
      const ushort* p = U1pk + (((size_t)jbp * 16 + kt) * 64 + L) * 16;
      uh[kt] = *(const short8*)(p); ul[kt] = *(const short8*)(p + 8);
    }
    float c_reg[2] = {0.f, 0.f};
    int fidx = ((L & 31) * 4 + ch) * FLS;

#pragma unroll 1
    for (int G = 0; G < 2 * TT; ++G) {
      if (G == TT) {              // layer 2: swap U; c2_0 = c1_T stays in c_reg
#pragma unroll
        for (int kt = 0; kt < 16; ++kt) {
          const ushort* p = U2pk + (((size_t)jbp * 16 + kt) * 64 + L) * 16;
          uh[kt] = *(const short8*)(p); ul[kt] = *(const short8*)(p + 8);
        }
      }
      // poll: h(G-1) ready across ch-group; xz(G) ready from partner
      while (true) {
        int hf = AT_LD(hflags + fidx);
        int pf = AT_LD(pflags + pidx);
        if (__all((hf >= G) && (pf >= G + 1))) break;
      }
      asm volatile("" ::: "memory");
      // xz for this step (4-slot ring, bypass loads; bias already included)
      float xzv[2][4];
#pragma unroll
      for (int ct = 0; ct < 2; ++ct) {
        const u64* xp = (const u64*)(xzr + ((size_t)(G & 3) * HB +
                                            (size_t)j * BB + col0 + ct * 16));
        u64 a = AT_LD(xp), c = AT_LD(xp + 1);
        xzv[ct][0] = __uint_as_float((uint)a);
        xzv[ct][1] = __uint_as_float((uint)(a >> 32));
        xzv[ct][2] = __uint_as_float((uint)c);
        xzv[ct][3] = __uint_as_float((uint)(c >> 32));
      }
#pragma unroll 1
      for (int ct = 0; ct < 2; ++ct) {
        int colc = col0 + ct * 16;
        f32x4 A0 = {0.f, 0.f, 0.f, 0.f}, A1 = A0, A2 = A0;
        if (G != 0) {
          uint wv[16][8];         // 16-deep prefetch (128 VGPR)
          if (G < TT) {           // phase A: seq, write-once -> plain loads
            const uint* hc = seq + (size_t)(G - 1) * HB + (size_t)(q * 8) * BB + colc;
#pragma unroll
            for (int kt = 0; kt < 16; ++kt)
#pragma unroll
              for (int u = 0; u < 8; ++u)
                wv[kt][u] = hc[(size_t)(kt * 32 + u) * BB];
          } else {                // phase B: ring, reused addrs -> atomic loads
            const uint* hc = ring + (size_t)((G - 1) & 3) * HB + (size_t)(q * 8) * BB + colc;
#pragma unroll
            for (int kt = 0; kt < 16; ++kt)
#pragma unroll
              for (int u = 0; u < 8; ++u)
                wv[kt][u] = AT_LD(&hc[(size_t)(kt * 32 + u) * BB]);
          }
#pragma unroll
          for (int kt = 0; kt < 16; ++kt) {
            short8 bh, bl;
            split8(wv[kt], bh, bl);
            A0 = MFMA(uh[kt], bh, A0, 0, 0, 0);
            A1 = MFMA(ul[kt], bh, A1, 0, 0, 0);
            A2 = MFMA(uh[kt], bl, A2, 0, 0, 0);
          }
        }
        float z0 = A0.x + A1.x + A2.x + xzv[ct][0];
        float z1 = A0.y + A1.y + A2.y + xzv[ct][1];
        float z2 = A0.z + A1.z + A2.z + xzv[ct][2];
        float z3 = A0.w + A1.w + A2.w + xzv[ct][3];
        float ig = 1.f / (1.f + __expf(-z0));
        float fg = 1.f / (1.f + __expf(-z1));
        float gg = tanhf(z2);
        float og = 1.f / (1.f + __expf(-z3));
        c_reg[ct] = fg * c_reg[ct] + ig * gg;
        float hn = og * tanhf(c_reg[ct]);
        ushort hh = f2bf(hn);
        uint word = (((uint)hh) << 16) | (uint)f2bf(hn - bfh(hh));
        if (G < TT) {
          AT_ST(&seq[(size_t)G * HB + (size_t)j * BB + colc], word);
          if (G == TT - 1)        // seed h2(-1) into ring slot 3
            AT_ST(&ring[(size_t)3 * HB + (size_t)j * BB + colc], word);
        } else {
          AT_ST(&ring[(size_t)(G & 3) * HB + (size_t)j * BB + colc], word);
        }
      }
      __syncthreads();            // drain all 4 waves' stores before the flag
      if (tid == 0) AT_ST(hflags + pidx, G + 1);
    }
  } else {
    // ---------------- PROJ block ----------------
#pragma unroll
    for (int kt = 0; kt < 4; ++kt) {
      const ushort* p = W1pk + (((size_t)jbp * 4 + kt) * 64 + L) * 16;
      uh[kt] = *(const short8*)(p); ul[kt] = *(const short8*)(p + 8);
    }
    float4 bv = *(const float4*)(bp1 + j * 4);

#pragma unroll 1
    for (int G = 0; G < 2 * TT; ++G) {
      if (G == TT) {              // layer 2: W2 frags + bias
#pragma unroll
        for (int kt = 0; kt < 16; ++kt) {
          const ushort* p = W2pk + (((size_t)jbp * 16 + kt) * 64 + L) * 16;
          uh[kt] = *(const short8*)(p); ul[kt] = *(const short8*)(p + 8);
        }
        bv = *(const float4*)(bp2 + j * 4);
      }
      // throttle: slot G&3 consumed by partner at step G-4 -> hflag >= G-3
      if (G >= 4) {
        while (AT_LD(hflags + pidx) < G - 3) __builtin_amdgcn_s_sleep(2);
      }
      asm volatile("" ::: "memory");
#pragma unroll 1
      for (int ct = 0; ct < 2; ++ct) {
        int colc = col0 + ct * 16;
        f32x4 P0 = {0.f, 0.f, 0.f, 0.f}, P1 = P0, P2 = P0;
        if (G < TT) {
          // xz1(G) = W1 * x(G): split fp32 x on the fly (slack-bound)
          const float* xp = x + ((size_t)colc * TT + G) * FF + q * 8;
#pragma unroll
          for (int kt = 0; kt < 4; ++kt) {
            float4 v0 = *(const float4*)(xp + kt * 32);
            float4 v1 = *(const float4*)(xp + kt * 32 + 4);
            float xf[8] = {v0.x, v0.y, v0.z, v0.w, v1.x, v1.y, v1.z, v1.w};
            short8 xh, xl;
#pragma unroll
            for (int u = 0; u < 8; ++u) {
              ushort hi = f2bf(xf[u]);
              xl[u] = (short)f2bf(xf[u] - bfh(hi));
              xh[u] = (short)hi;
            }
            P0 = MFMA(uh[kt], xh, P0, 0, 0, 0);
            P1 = MFMA(ul[kt], xh, P1, 0, 0, 0);
            P2 = MFMA(uh[kt], xl, P2, 0, 0, 0);
          }
        } else {
          // xz2(sp) = W2 * h1(sp): seq final -> plain loads
          int sp = G - TT;
          const uint* hc = seq + (size_t)sp * HB + (size_t)(q * 8) * BB + colc;
          uint wv[16][8];
#pragma unroll
          for (int kt = 0; kt < 16; ++kt)
#pragma unroll
            for (int u = 0; u < 8; ++u)
              wv[kt][u] = hc[(size_t)(kt * 32 + u) * BB];
#pragma unroll
          for (int kt = 0; kt < 16; ++kt) {
            short8 bh, bl;
            split8(wv[kt], bh, bl);
            P0 = MFMA(uh[kt], bh, P0, 0, 0, 0);
            P1 = MFMA(ul[kt], bh, P1, 0, 0, 0);
            P2 = MFMA(uh[kt], bl, P2, 0, 0, 0);
          }
        }
        float o0 = P0.x + P1.x + P2.x + bv.x;
        float o1 = P0.y + P1.y + P2.y + bv.y;
        float o2 = P0.z + P1.z + P2.z + bv.z;
        float o3 = P0.w + P1.w + P2.w + bv.w;
        u64* dp = (u64*)(xzr + ((size_t)(G & 3) * HB + (size_t)j * BB + colc));
        AT_ST(dp, pk2f(o0, o1));
        AT_ST(dp + 1, pk2f(o2, o3));
      }
      __syncthreads();
      if (tid == 0) AT_ST(pflags + pidx, G + 1);
    }
  }
}

// ---------------- dense + softmax (reads ring slot 3 words) ----------------
__global__ __launch_bounds__(64) void k_dense(const uint* __restrict__ h2,
                                              const float* __restrict__ Wd,
                                              const float* __restrict__ bd,
                                              float* __restrict__ out) {
  int b = blockIdx.x * 64 + threadIdx.x;
  float acc[10];
#pragma unroll
  for (int c = 0; c < 10; ++c) acc[c] = bd[c];
  for (int k = 0; k < HH; ++k) {
    uint w = h2[k * BB + b];
    float hv = __uint_as_float(w & 0xffff0000u) + __uint_as_float(w << 16);
#pragma unroll
    for (int c = 0; c < 10; ++c) acc[c] = fmaf(hv, Wd[k * 10 + c], acc[c]);
  }
  float m = acc[0];
#pragma unroll
  for (int c = 1; c < 10; ++c) m = fmaxf(m, acc[c]);
  float s = 0.f;
#pragma unroll
  for (int c = 0; c < 10; ++c) { acc[c] = __expf(acc[c] - m); s += acc[c]; }
  float inv = 1.f / s;
#pragma unroll
  for (int c = 0; c < 10; ++c) out[b * 10 + c] = acc[c] * inv;
}

// ---------------- host ----------------
extern "C" void kernel_launch(void* const* d_in, const int* in_sizes, int n_in,
                              void* d_out, int out_size, void* d_ws, size_t ws_size,
                              hipStream_t stream) {
  const float* x  = (const float*)d_in[0];
  const float* W1 = (const float*)d_in[1];
  const float* U1 = (const float*)d_in[2];
  const float* b1 = (const float*)d_in[3];
  const float* W2 = (const float*)d_in[4];
  const float* U2 = (const float*)d_in[5];
  const float* b2 = (const float*)d_in[6];
  const float* Wd = (const float*)d_in[7];
  const float* bd = (const float*)d_in[8];
  float* out = (float*)d_out;

  // workspace layout (~147 MB, < proven 181 MB)
  uint*   seq   = (uint*)d_ws;                      // [512][HB]   128 MB
  uint*   ring  = seq + (size_t)TT * HB;            // [4][HB]       1 MB
  float4* xzr   = (float4*)(ring + (size_t)4 * HB); // [4][HB] f4    4 MB
  ushort* W1pk  = (ushort*)(xzr + (size_t)4 * HB);  //   524,288 ush
  ushort* U1pk  = W1pk + (size_t)524288;            // 2,097,152 ush
  ushort* U2pk  = U1pk + (size_t)2097152;           // 2,097,152 ush
  ushort* W2pk  = U2pk + (size_t)2097152;           // 2,097,152 ush
  float*  bp1   = (float*)(W2pk + (size_t)2097152); // 2,048 f
  float*  bp2   = bp1 + NR;                         // 2,048 f
  int*    hflags = (int*)(bp2 + NR);                // 128*FLS ints
  int*    pflags = hflags + 128 * FLS;              // 128*FLS ints

  k_zero<<<16, 256, 0, stream>>>((float*)hflags, 2 * 128 * FLS);
  k_rearr_b<<<8, 256, 0, stream>>>(b1, bp1);
  k_rearr_b<<<8, 256, 0, stream>>>(b2, bp2);
  k_pack_A<<<1024, 256, 0, stream>>>(W1, W1pk, 2);   // K=128 -> 4 k-tiles
  k_pack_A<<<4096, 256, 0, stream>>>(U1, U1pk, 4);   // K=512 -> 16 k-tiles
  k_pack_A<<<4096, 256, 0, stream>>>(U2, U2pk, 4);
  k_pack_A<<<4096, 256, 0, stream>>>(W2, W2pk, 4);

  k_fused<<<256, 256, 0, stream>>>(x, W1pk, U1pk, bp1, W2pk, U2pk, bp2,
                                   seq, ring, xzr, hflags, pflags);
  k_dense<<<2, 64, 0, stream>>>(ring + (size_t)3 * HB, Wd, bd, out);
}

// Round 4
// 5714.503 us; speedup vs baseline: 1.4699x; 1.1157x over previous
//
#include <hip/hip_runtime.h>
#include <math.h>

#define BB 128
#define TT 512
#define FF 128
#define HH 512
#define NR 2048      // gate rows, row = 4*j + g
#define HB (HH*BB)   // 65536 words per h state
#define FLS 16       // flag stride (ints): one flag per 64B line

typedef __attribute__((ext_vector_type(8))) short short8;   // 8 bf16
typedef __attribute__((ext_vector_type(4))) float f32x4;    // MFMA C/D frag
typedef unsigned int uint;
typedef unsigned short ushort;
typedef unsigned long long u64;

#define MFMA __builtin_amdgcn_mfma_f32_16x16x32_bf16
#define AT_LD(p)   __hip_atomic_load((p), __ATOMIC_RELAXED, __HIP_MEMORY_SCOPE_AGENT)
#define AT_ST(p,v) __hip_atomic_store((p), (v), __ATOMIC_RELAXED, __HIP_MEMORY_SCOPE_AGENT)
#define PLD(p)     (*(p))

__device__ __forceinline__ ushort f2bf(float f) {           // fp32 -> bf16 RNE
  uint u = __float_as_uint(f);
  u += 0x7fff + ((u >> 16) & 1);
  return (ushort)(u >> 16);
}
__device__ __forceinline__ float bfh(ushort h) { return __uint_as_float(((uint)h) << 16); }
__device__ __forceinline__ u64 pk2f(float a, float b) {
  return ((u64)__float_as_uint(b) << 32) | (u64)__float_as_uint(a);
}
__device__ __forceinline__ float ftanh(float v) {           // branch-free tanh
  float t = __expf(2.f * v);
  return 1.f - 2.f / (t + 1.f);
}
// 8 packed words (hi16|lo16) -> hi/lo short8 B-frags via v_perm (1 op/dword)
__device__ __forceinline__ void split8(const uint* w, short8& bh, short8& bl) {
  union { short8 v; uint d[4]; } H, Lo;
#pragma unroll
  for (int d = 0; d < 4; ++d) {
    H.d[d]  = __builtin_amdgcn_perm(w[2 * d + 1], w[2 * d], 0x07060302u);
    Lo.d[d] = __builtin_amdgcn_perm(w[2 * d + 1], w[2 * d], 0x05040100u);
  }
  bh = H.v; bl = Lo.v;
}

// ---------------- prep kernels ----------------

__global__ __launch_bounds__(256) void k_zero(float* __restrict__ p, int n) {
  int i = blockIdx.x * 256 + threadIdx.x;
  if (i < n) p[i] = 0.f;
}

// bias [2048] (col = g*512 + j) -> bp[j*4+g]
__global__ __launch_bounds__(256) void k_rearr_b(const float* __restrict__ src,
                                                 float* __restrict__ dst) {
  int idx = blockIdx.x * 256 + threadIdx.x;   // 2048
  int j = idx & 511, g = idx >> 9;
  dst[j * 4 + g] = src[idx];
}

// [K][2048] matrix -> A-fragment order, bf16 hi/lo split. KT=1<<ktsh k-tiles.
__global__ __launch_bounds__(256) void k_pack_A(const float* __restrict__ src,
                                                ushort* __restrict__ dst, int ktsh) {
  int idx = blockIdx.x * 256 + threadIdx.x;
  int KTm1 = (1 << ktsh) - 1;
  int j8 = idx & 7;
  int L = (idx >> 3) & 63;
  int kt = (idx >> 9) & KTm1;
  int jb = idx >> (9 + ktsh);
  int k = kt * 32 + (L >> 4) * 8 + j8;
  int m = L & 15;
  int j = jb * 4 + (m >> 2);
  int g = m & 3;
  float v = src[(size_t)k * NR + g * HH + j];
  ushort hi = f2bf(v);
  ushort lo = f2bf(v - bfh(hi));
  size_t base = ((size_t)((jb << ktsh) + kt) * 64 + L) * 16;
  dst[base + j8] = hi;
  dst[base + 8 + j8] = lo;
}

// ---------------- fused persistent 2-layer LSTM, specialized blocks ----------
// Protocol identical to R3 (passed). Changes: (1) NO runtime-indexed private
// arrays in hot loops (named scalars c0/c1, xz**, wd0/wd1; macro-flattened
// ct=0/1) -> no LDS demotion; (2) xz ring deepened to 8 slots so proj runs
// ahead and rec's pflag check is pre-satisfied; (3) branch-free tanh.
__global__ __launch_bounds__(256, 1) void k_fused(
    const float* __restrict__ x,
    const ushort* __restrict__ W1pk, const ushort* __restrict__ U1pk,
    const float* __restrict__ bp1,
    const ushort* __restrict__ W2pk, const ushort* __restrict__ U2pk,
    const float* __restrict__ bp2,
    uint* __restrict__ seq, uint* __restrict__ ring,
    float4* __restrict__ xzr,                              // 8-slot gate ring
    int* __restrict__ hflags, int* __restrict__ pflags) {
  int tid = threadIdx.x;
  int L = tid & 63;
  int w = tid >> 6;
  int q = L >> 4, n = L & 15;
  bool isrec = (blockIdx.x < 128);
  int b = isrec ? blockIdx.x : (blockIdx.x - 128);
  int ch = b & 3, jb4 = b >> 2;
  int jbp = jb4 * 4 + w;          // this wave's row tile
  int j = jbp * 4 + q;            // this lane's hidden unit
  int col0 = ch * 32 + n;         // col-tile 0; tile 1 at +16
  int pidx = b * FLS;

  short8 uh[16], ul[16];          // resident A-frags (128 VGPR)

// rec compute for one col-tile: loads (LD = PLD|AT_LD) + 48 MFMA + act.
// All indices compile-time; wv lives in registers.
#define RECCT(COLC, CREF, X0, X1, X2, X3, LD, WORD) {                    \
    f32x4 A0 = {0.f, 0.f, 0.f, 0.f}, A1 = A0, A2 = A0;                   \
    if (G != 0) {                                                        \
      uint wv[16][8];                                                    \
      const uint* hc = hsrc + (size_t)(q * 8) * BB + (COLC);             \
      _Pragma("unroll")                                                  \
      for (int kt = 0; kt < 16; ++kt)                                    \
        _Pragma("unroll")                                                \
        for (int u = 0; u < 8; ++u)                                      \
          wv[kt][u] = LD(hc + (size_t)(kt * 32 + u) * BB);               \
      _Pragma("unroll")                                                  \
      for (int kt = 0; kt < 16; ++kt) {                                  \
        short8 bh, bl;                                                   \
        split8(wv[kt], bh, bl);                                          \
        A0 = MFMA(uh[kt], bh, A0, 0, 0, 0);                              \
        A1 = MFMA(ul[kt], bh, A1, 0, 0, 0);                              \
        A2 = MFMA(uh[kt], bl, A2, 0, 0, 0);                              \
      }                                                                  \
    }                                                                    \
    float z0 = A0.x + A1.x + A2.x + (X0);                                \
    float z1 = A0.y + A1.y + A2.y + (X1);                                \
    float z2 = A0.z + A1.z + A2.z + (X2);                                \
    float z3 = A0.w + A1.w + A2.w + (X3);                                \
    float ig = 1.f / (1.f + __expf(-z0));                                \
    float fg = 1.f / (1.f + __expf(-z1));                                \
    float gg = ftanh(z2);                                                \
    float og = 1.f / (1.f + __expf(-z3));                                \
    (CREF) = fg * (CREF) + ig * gg;                                      \
    float hn = og * ftanh(CREF);                                         \
    ushort hh = f2bf(hn);                                                \
    (WORD) = (((uint)hh) << 16) | (uint)f2bf(hn - bfh(hh));              \
  }

  if (isrec) {
#pragma unroll
    for (int kt = 0; kt < 16; ++kt) {
      const ushort* p = U1pk + (((size_t)jbp * 16 + kt) * 64 + L) * 16;
      uh[kt] = *(const short8*)(p); ul[kt] = *(const short8*)(p + 8);
    }
    float c0 = 0.f, c1 = 0.f;
    int fidx = ((L & 31) * 4 + ch) * FLS;

#pragma unroll 1
    for (int G = 0; G < 2 * TT; ++G) {
      if (G == TT) {              // layer 2: swap U; c2_0 = c1_T stays in c0/c1
#pragma unroll
        for (int kt = 0; kt < 16; ++kt) {
          const ushort* p = U2pk + (((size_t)jbp * 16 + kt) * 64 + L) * 16;
          uh[kt] = *(const short8*)(p); ul[kt] = *(const short8*)(p + 8);
        }
      }
      // poll: h(G-1) ready across ch-group; xz(G) ready from partner
      while (true) {
        int hf = AT_LD(hflags + fidx);
        int pf = AT_LD(pflags + pidx);
        if (__all((hf >= G) && (pf >= G + 1))) break;
      }
      asm volatile("" ::: "memory");
      // xz for this step (8-slot ring, bypass loads; bias included)
      const u64* xpa = (const u64*)(xzr + ((size_t)(G & 7) * HB + (size_t)j * BB + col0));
      const u64* xpb = (const u64*)(xzr + ((size_t)(G & 7) * HB + (size_t)j * BB + col0 + 16));
      u64 qa0 = AT_LD(xpa), qa1 = AT_LD(xpa + 1);
      u64 qb0 = AT_LD(xpb), qb1 = AT_LD(xpb + 1);
      float xz00 = __uint_as_float((uint)qa0), xz01 = __uint_as_float((uint)(qa0 >> 32));
      float xz02 = __uint_as_float((uint)qa1), xz03 = __uint_as_float((uint)(qa1 >> 32));
      float xz10 = __uint_as_float((uint)qb0), xz11 = __uint_as_float((uint)(qb0 >> 32));
      float xz12 = __uint_as_float((uint)qb1), xz13 = __uint_as_float((uint)(qb1 >> 32));

      uint wd0, wd1;
      if (G < TT) {               // phase A: seq, write-once -> plain loads
        const uint* hsrc = seq + (size_t)(G - 1) * HB;
        RECCT(col0,      c0, xz00, xz01, xz02, xz03, PLD, wd0);
        RECCT(col0 + 16, c1, xz10, xz11, xz12, xz13, PLD, wd1);
        AT_ST(&seq[(size_t)G * HB + (size_t)j * BB + col0], wd0);
        AT_ST(&seq[(size_t)G * HB + (size_t)j * BB + col0 + 16], wd1);
        if (G == TT - 1) {        // seed h2(-1) into ring slot 3
          AT_ST(&ring[(size_t)3 * HB + (size_t)j * BB + col0], wd0);
          AT_ST(&ring[(size_t)3 * HB + (size_t)j * BB + col0 + 16], wd1);
        }
      } else {                    // phase B: ring, reused addrs -> atomic loads
        const uint* hsrc = ring + (size_t)((G - 1) & 3) * HB;
        RECCT(col0,      c0, xz00, xz01, xz02, xz03, AT_LD, wd0);
        RECCT(col0 + 16, c1, xz10, xz11, xz12, xz13, AT_LD, wd1);
        AT_ST(&ring[(size_t)(G & 3) * HB + (size_t)j * BB + col0], wd0);
        AT_ST(&ring[(size_t)(G & 3) * HB + (size_t)j * BB + col0 + 16], wd1);
      }
      __syncthreads();            // drain all 4 waves' stores before the flag
      if (tid == 0) AT_ST(hflags + pidx, G + 1);
    }
  } else {
    // ---------------- PROJ block ----------------
#pragma unroll
    for (int kt = 0; kt < 4; ++kt) {
      const ushort* p = W1pk + (((size_t)jbp * 4 + kt) * 64 + L) * 16;
      uh[kt] = *(const short8*)(p); ul[kt] = *(const short8*)(p + 8);
    }
    float4 bv = *(const float4*)(bp1 + j * 4);

// phase-A proj for one col-tile: xz1 = W1 * x(G) + b1
#define PROJA(COLC) {                                                    \
    f32x4 P0 = {0.f, 0.f, 0.f, 0.f}, P1 = P0, P2 = P0;                   \
    const float* xp = x + ((size_t)(COLC) * TT + G) * FF + q * 8;        \
    _Pragma("unroll")                                                    \
    for (int kt = 0; kt < 4; ++kt) {                                     \
      float4 v0 = *(const float4*)(xp + kt * 32);                        \
      float4 v1 = *(const float4*)(xp + kt * 32 + 4);                    \
      float xf[8] = {v0.x, v0.y, v0.z, v0.w, v1.x, v1.y, v1.z, v1.w};    \
      short8 xh, xl;                                                     \
      _Pragma("unroll")                                                  \
      for (int u = 0; u < 8; ++u) {                                      \
        ushort hi = f2bf(xf[u]);                                         \
        xl[u] = (short)f2bf(xf[u] - bfh(hi));                            \
        xh[u] = (short)hi;                                               \
      }                                                                  \
      P0 = MFMA(uh[kt], xh, P0, 0, 0, 0);                                \
      P1 = MFMA(ul[kt], xh, P1, 0, 0, 0);                                \
      P2 = MFMA(uh[kt], xl, P2, 0, 0, 0);                                \
    }                                                                    \
    float o0 = P0.x + P1.x + P2.x + bv.x;                                \
    float o1 = P0.y + P1.y + P2.y + bv.y;                                \
    float o2 = P0.z + P1.z + P2.z + bv.z;                                \
    float o3 = P0.w + P1.w + P2.w + bv.w;                                \
    u64* dp = (u64*)(xzr + ((size_t)(G & 7) * HB + (size_t)j * BB + (COLC))); \
    AT_ST(dp, pk2f(o0, o1));                                             \
    AT_ST(dp + 1, pk2f(o2, o3));                                         \
  }

// phase-B proj for one col-tile: xz2 = W2 * h1(sp) + b2 (seq final -> plain)
#define PROJB(COLC) {                                                    \
    f32x4 P0 = {0.f, 0.f, 0.f, 0.f}, P1 = P0, P2 = P0;                   \
    uint wv[16][8];                                                      \
    const uint* hc = seq + (size_t)sp * HB + (size_t)(q * 8) * BB + (COLC); \
    _Pragma("unroll")                                                    \
    for (int kt = 0; kt < 16; ++kt)                                      \
      _Pragma("unroll")                                                  \
      for (int u = 0; u < 8; ++u)                                        \
        wv[kt][u] = hc[(size_t)(kt * 32 + u) * BB];                      \
    _Pragma("unroll")                                                    \
    for (int kt = 0; kt < 16; ++kt) {                                    \
      short8 bh, bl;                                                     \
      split8(wv[kt], bh, bl);                                            \
      P0 = MFMA(uh[kt], bh, P0, 0, 0, 0);                                \
      P1 = MFMA(ul[kt], bh, P1, 0, 0, 0);                                \
      P2 = MFMA(uh[kt], bl, P2, 0, 0, 0);                                \
    }                                                                    \
    float o0 = P0.x + P1.x + P2.x + bv.x;                                \
    float o1 = P0.y + P1.y + P2.y + bv.y;                                \
    float o2 = P0.z + P1.z + P2.z + bv.z;                                \
    float o3 = P0.w + P1.w + P2.w + bv.w;                                \
    u64* dp = (u64*)(xzr + ((size_t)(G & 7) * HB + (size_t)j * BB + (COLC))); \
    AT_ST(dp, pk2f(o0, o1));                                             \
    AT_ST(dp + 1, pk2f(o2, o3));                                         \
  }

#pragma unroll 1
    for (int G = 0; G < 2 * TT; ++G) {
      if (G == TT) {              // layer 2: W2 frags + bias
#pragma unroll
        for (int kt = 0; kt < 16; ++kt) {
          const ushort* p = W2pk + (((size_t)jbp * 16 + kt) * 64 + L) * 16;
          uh[kt] = *(const short8*)(p); ul[kt] = *(const short8*)(p + 8);
        }
        bv = *(const float4*)(bp2 + j * 4);
      }
      // throttle: slot G&7 last consumed by partner at step G-8 -> hflag >= G-7
      if (G >= 8) {
        while (AT_LD(hflags + pidx) < G - 7) __builtin_amdgcn_s_sleep(1);
      }
      asm volatile("" ::: "memory");
      if (G < TT) {
        PROJA(col0);
        PROJA(col0 + 16);
      } else {
        int sp = G - TT;
        PROJB(col0);
        PROJB(col0 + 16);
      }
      __syncthreads();
      if (tid == 0) AT_ST(pflags + pidx, G + 1);
    }
  }
}

// ---------------- dense + softmax (reads ring slot 3 words) ----------------
__global__ __launch_bounds__(64) void k_dense(const uint* __restrict__ h2,
                                              const float* __restrict__ Wd,
                                              const float* __restrict__ bd,
                                              float* __restrict__ out) {
  int b = blockIdx.x * 64 + threadIdx.x;
  float acc[10];
#pragma unroll
  for (int c = 0; c < 10; ++c) acc[c] = bd[c];
  for (int k = 0; k < HH; ++k) {
    uint w = h2[k * BB + b];
    float hv = __uint_as_float(w & 0xffff0000u) + __uint_as_float(w << 16);
#pragma unroll
    for (int c = 0; c < 10; ++c) acc[c] = fmaf(hv, Wd[k * 10 + c], acc[c]);
  }
  float m = acc[0];
#pragma unroll
  for (int c = 1; c < 10; ++c) m = fmaxf(m, acc[c]);
  float s = 0.f;
#pragma unroll
  for (int c = 0; c < 10; ++c) { acc[c] = __expf(acc[c] - m); s += acc[c]; }
  float inv = 1.f / s;
#pragma unroll
  for (int c = 0; c < 10; ++c) out[b * 10 + c] = acc[c] * inv;
}

// ---------------- host ----------------
extern "C" void kernel_launch(void* const* d_in, const int* in_sizes, int n_in,
                              void* d_out, int out_size, void* d_ws, size_t ws_size,
                              hipStream_t stream) {
  const float* x  = (const float*)d_in[0];
  const float* W1 = (const float*)d_in[1];
  const float* U1 = (const float*)d_in[2];
  const float* b1 = (const float*)d_in[3];
  const float* W2 = (const float*)d_in[4];
  const float* U2 = (const float*)d_in[5];
  const float* b2 = (const float*)d_in[6];
  const float* Wd = (const float*)d_in[7];
  const float* bd = (const float*)d_in[8];
  float* out = (float*)d_out;

  // workspace layout (~157 MB, < proven 181 MB)
  uint*   seq   = (uint*)d_ws;                      // [512][HB]   128 MB
  uint*   ring  = seq + (size_t)TT * HB;            // [4][HB]       1 MB
  float4* xzr   = (float4*)(ring + (size_t)4 * HB); // [8][HB] f4    8 MB
  ushort* W1pk  = (ushort*)(xzr + (size_t)8 * HB);  //   524,288 ush
  ushort* U1pk  = W1pk + (size_t)524288;            // 2,097,152 ush
  ushort* U2pk  = U1pk + (size_t)2097152;           // 2,097,152 ush
  ushort* W2pk  = U2pk + (size_t)2097152;           // 2,097,152 ush
  float*  bp1   = (float*)(W2pk + (size_t)2097152); // 2,048 f
  float*  bp2   = bp1 + NR;                         // 2,048 f
  int*    hflags = (int*)(bp2 + NR);                // 128*FLS ints
  int*    pflags = hflags + 128 * FLS;              // 128*FLS ints

  k_zero<<<16, 256, 0, stream>>>((float*)hflags, 2 * 128 * FLS);
  k_rearr_b<<<8, 256, 0, stream>>>(b1, bp1);
  k_rearr_b<<<8, 256, 0, stream>>>(b2, bp2);
  k_pack_A<<<1024, 256, 0, stream>>>(W1, W1pk, 2);   // K=128 -> 4 k-tiles
  k_pack_A<<<4096, 256, 0, stream>>>(U1, U1pk, 4);   // K=512 -> 16 k-tiles
  k_pack_A<<<4096, 256, 0, stream>>>(U2, U2pk, 4);
  k_pack_A<<<4096, 256, 0, stream>>>(W2, W2pk, 4);

  k_fused<<<256, 256, 0, stream>>>(x, W1pk, U1pk, bp1, W2pk, U2pk, bp2,
                                   seq, ring, xzr, hflags, pflags);
  k_dense<<<2, 64, 0, stream>>>(ring + (size_t)3 * HB, Wd, bd, out);
}

// Round 5
// 5205.711 us; speedup vs baseline: 1.6135x; 1.0977x over previous
//
#include <hip/hip_runtime.h>
#include <math.h>

#define BB 128
#define TT 512
#define FF 128
#define HH 512
#define NR 2048      // gate rows, row = 4*j + g
#define HB (HH*BB)   // 65536 words per h state
#define FLS 16       // flag stride (ints): one flag per 64B line

typedef __attribute__((ext_vector_type(8))) short short8;   // 8 bf16
typedef __attribute__((ext_vector_type(4))) float f32x4;    // MFMA C/D frag
typedef unsigned int uint;
typedef unsigned short ushort;
typedef unsigned long long u64;

#define MFMA __builtin_amdgcn_mfma_f32_16x16x32_bf16
#define AT_LD(p)   __hip_atomic_load((p), __ATOMIC_RELAXED, __HIP_MEMORY_SCOPE_AGENT)
#define AT_ST(p,v) __hip_atomic_store((p), (v), __ATOMIC_RELAXED, __HIP_MEMORY_SCOPE_AGENT)
#define PLD(p)     (*(p))

__device__ __forceinline__ ushort f2bf(float f) {           // fp32 -> bf16 RNE
  uint u = __float_as_uint(f);
  u += 0x7fff + ((u >> 16) & 1);
  return (ushort)(u >> 16);
}
__device__ __forceinline__ float bfh(ushort h) { return __uint_as_float(((uint)h) << 16); }
__device__ __forceinline__ u64 pk2f(float a, float b) {
  return ((u64)__float_as_uint(b) << 32) | (u64)__float_as_uint(a);
}
__device__ __forceinline__ float ftanh(float v) {           // branch-free tanh
  float t = __expf(2.f * v);
  return 1.f - 2.f / (t + 1.f);
}
// 8 packed words (hi16|lo16) -> hi/lo short8 B-frags via v_perm (1 op/dword)
__device__ __forceinline__ void split8(const uint* w, short8& bh, short8& bl) {
  union { short8 v; uint d[4]; } H, Lo;
#pragma unroll
  for (int d = 0; d < 4; ++d) {
    H.d[d]  = __builtin_amdgcn_perm(w[2 * d + 1], w[2 * d], 0x07060302u);
    Lo.d[d] = __builtin_amdgcn_perm(w[2 * d + 1], w[2 * d], 0x05040100u);
  }
  bh = H.v; bl = Lo.v;
}

// ---------------- prep kernels ----------------

__global__ __launch_bounds__(256) void k_zero(float* __restrict__ p, int n) {
  int i = blockIdx.x * 256 + threadIdx.x;
  if (i < n) p[i] = 0.f;
}

// bias [2048] (col = g*512 + j) -> bp[j*4+g]
__global__ __launch_bounds__(256) void k_rearr_b(const float* __restrict__ src,
                                                 float* __restrict__ dst) {
  int idx = blockIdx.x * 256 + threadIdx.x;   // 2048
  int j = idx & 511, g = idx >> 9;
  dst[j * 4 + g] = src[idx];
}

// [K][2048] matrix -> A-fragment order, bf16 hi/lo split. KT=1<<ktsh k-tiles.
__global__ __launch_bounds__(256) void k_pack_A(const float* __restrict__ src,
                                                ushort* __restrict__ dst, int ktsh) {
  int idx = blockIdx.x * 256 + threadIdx.x;
  int KTm1 = (1 << ktsh) - 1;
  int j8 = idx & 7;
  int L = (idx >> 3) & 63;
  int kt = (idx >> 9) & KTm1;
  int jb = idx >> (9 + ktsh);
  int k = kt * 32 + (L >> 4) * 8 + j8;
  int m = L & 15;
  int j = jb * 4 + (m >> 2);
  int g = m & 3;
  float v = src[(size_t)k * NR + g * HH + j];
  ushort hi = f2bf(v);
  ushort lo = f2bf(v - bfh(hi));
  size_t base = ((size_t)((jb << ktsh) + kt) * 64 + L) * 16;
  dst[base + j8] = hi;
  dst[base + 8 + j8] = lo;
}

// ---------------- fused persistent 2-layer LSTM, specialized + K-split ------
// 256 blocks x 256 thr (1/CU). Blocks 0..127 REC, 128..255 PROJ (partner b).
// Block b: ch=b&3 (32 cols at ch*32), jb4=b>>2 (16 units at jb4*16).
// K-SPLIT WAVES: wave w -> (p=w>>1: row-tile pair, h=w&1: K-half). Each wave
// computes PARTIAL z for row-tiles {2p,2p+1}, both col-tiles, K rows
// [256h,256h+256) -> 128 B-load instrs + 96 MFMA per wave (loads HALVED vs
// R4; per-block h traffic 256->128 KB). Partials exchanged via 8 KB LDS
// (xch[rt][ct][lane]); wave (p,h) keeps local rt 2p+h, gives 2p+(1-h).
// Each wave polls ONLY its K-half's 16 producer flags -> early start; the 4
// waves jointly cover all 32 flags before the block flag store, so block
// skew stays <=1 and the 4-slot ring argument is unchanged. All layouts &
// the flag/atomic protocol are R4-proven.
__global__ __launch_bounds__(256, 1) void k_fused(
    const float* __restrict__ x,
    const ushort* __restrict__ W1pk, const ushort* __restrict__ U1pk,
    const float* __restrict__ bp1,
    const ushort* __restrict__ W2pk, const ushort* __restrict__ U2pk,
    const float* __restrict__ bp2,
    uint* __restrict__ seq, uint* __restrict__ ring,
    float4* __restrict__ xzr,                              // 8-slot gate ring
    int* __restrict__ hflags, int* __restrict__ pflags) {
  int tid = threadIdx.x;
  int L = tid & 63;
  int w = tid >> 6;
  int q = L >> 4, n = L & 15;
  int h = w & 1, p = w >> 1;      // K-half, row-tile pair
  bool isrec = (blockIdx.x < 128);
  int b = isrec ? blockIdx.x : (blockIdx.x - 128);
  int ch = b & 3, jb4 = b >> 2;
  int rt0 = jb4 * 4 + 2 * p;      // partial row-tiles rt0, rt0+1
  int jbp_own = rt0 + h;          // row-tile this wave finishes
  int j_own = jbp_own * 4 + q;    // this lane's hidden unit (epilogue)
  int col0 = ch * 32 + n;         // col-tile 0; tile 1 at +16
  int pidx = b * FLS;
  int rgive = 2 * p + 1 - h;      // LDS slot given away (block-local rt)
  int rkeep = 2 * p + h;

  __shared__ f32x4 xch[4][2][64]; // [local rt][ct][lane] partial exchange

  short8 uh[2][8], ul[2][8];      // resident A-frags: 2 rts x 8 kts (K-half)

// load + partial GEMM for one col-tile over this wave's K-half.
// HS must already include the +256h*BB row offset. ZP: f32x4[2] (per rt).
#define LOADMM(HS, LD, COLC, ZP) {                                       \
    uint wv[8][8];                                                       \
    const uint* hc = (HS) + (size_t)(q * 8) * BB + (COLC);               \
    _Pragma("unroll")                                                    \
    for (int kk = 0; kk < 8; ++kk)                                       \
      _Pragma("unroll")                                                  \
      for (int u = 0; u < 8; ++u)                                        \
        wv[kk][u] = LD(hc + (size_t)(kk * 32 + u) * BB);                 \
    f32x4 A0[2], A1[2], A2[2];                                           \
    _Pragma("unroll")                                                    \
    for (int r = 0; r < 2; ++r) {                                        \
      A0[r] = (f32x4){0.f, 0.f, 0.f, 0.f}; A1[r] = A0[r]; A2[r] = A0[r]; \
    }                                                                    \
    _Pragma("unroll")                                                    \
    for (int kk = 0; kk < 8; ++kk) {                                     \
      short8 bh, bl;                                                     \
      split8(wv[kk], bh, bl);                                            \
      _Pragma("unroll")                                                  \
      for (int r = 0; r < 2; ++r) {                                      \
        A0[r] = MFMA(uh[r][kk], bh, A0[r], 0, 0, 0);                     \
        A1[r] = MFMA(ul[r][kk], bh, A1[r], 0, 0, 0);                     \
        A2[r] = MFMA(uh[r][kk], bl, A2[r], 0, 0, 0);                     \
      }                                                                  \
    }                                                                    \
    ZP[0] = A0[0] + A1[0] + A2[0];                                       \
    ZP[1] = A0[1] + A1[1] + A2[1];                                       \
  }

// activation for one col-tile from a summed z (f32x4) + xz scalars
#define ACT(ZV, X0, X1, X2, X3, CREF, WORD) {                            \
    float z0_ = (ZV).x + (X0), z1_ = (ZV).y + (X1);                      \
    float z2_ = (ZV).z + (X2), z3_ = (ZV).w + (X3);                      \
    float ig = 1.f / (1.f + __expf(-z0_));                               \
    float fg = 1.f / (1.f + __expf(-z1_));                               \
    float gg = ftanh(z2_);                                               \
    float og = 1.f / (1.f + __expf(-z3_));                               \
    (CREF) = fg * (CREF) + ig * gg;                                      \
    float hn = og * ftanh(CREF);                                         \
    ushort hh = f2bf(hn);                                                \
    (WORD) = (((uint)hh) << 16) | (uint)f2bf(hn - bfh(hh));              \
  }

  if (isrec) {
#pragma unroll
    for (int r = 0; r < 2; ++r)
#pragma unroll
      for (int kk = 0; kk < 8; ++kk) {
        const ushort* pp = U1pk + (((size_t)(rt0 + r) * 16 + (8 * h + kk)) * 64 + L) * 16;
        uh[r][kk] = *(const short8*)(pp); ul[r][kk] = *(const short8*)(pp + 8);
      }
    float c0 = 0.f, c1 = 0.f;     // carried; c2_0 = c1_T at phase switch
    int fidx = ((16 * h + (L & 15)) * 4 + ch) * FLS;   // this K-half's flags

#pragma unroll 1
    for (int G = 0; G < 2 * TT; ++G) {
      if (G == TT) {
#pragma unroll
        for (int r = 0; r < 2; ++r)
#pragma unroll
          for (int kk = 0; kk < 8; ++kk) {
            const ushort* pp = U2pk + (((size_t)(rt0 + r) * 16 + (8 * h + kk)) * 64 + L) * 16;
            uh[r][kk] = *(const short8*)(pp); ul[r][kk] = *(const short8*)(pp + 8);
          }
      }
      // per-wave poll: this K-half's producers at >= G, partner xz at >= G+1
      while (true) {
        int hf = AT_LD(hflags + fidx);
        int pf = AT_LD(pflags + pidx);
        if (__all((hf >= G) && (pf >= G + 1))) break;
      }
      asm volatile("" ::: "memory");
      // xz for the owner unit (8-slot ring, bypass; long latency -> issue 1st)
      const u64* xpa = (const u64*)(xzr + ((size_t)(G & 7) * HB + (size_t)j_own * BB + col0));
      const u64* xpb = (const u64*)(xzr + ((size_t)(G & 7) * HB + (size_t)j_own * BB + col0 + 16));
      u64 qa0 = AT_LD(xpa), qa1 = AT_LD(xpa + 1);
      u64 qb0 = AT_LD(xpb), qb1 = AT_LD(xpb + 1);

      f32x4 zp0[2], zp1[2];       // partials per rt, ct0/ct1
      if (G != 0) {
        if (G < TT) {             // phase A: seq, write-once -> plain loads
          const uint* hs = seq + (size_t)(G - 1) * HB + (size_t)(256 * h) * BB;
          LOADMM(hs, PLD, col0, zp0);
          LOADMM(hs, PLD, col0 + 16, zp1);
        } else {                  // phase B: ring -> bypass atomic loads
          const uint* hs = ring + (size_t)((G - 1) & 3) * HB + (size_t)(256 * h) * BB;
          LOADMM(hs, AT_LD, col0, zp0);
          LOADMM(hs, AT_LD, col0 + 16, zp1);
        }
      } else {
        zp0[0] = (f32x4){0.f, 0.f, 0.f, 0.f}; zp0[1] = zp0[0];
        zp1[0] = zp0[0]; zp1[1] = zp0[0];
      }
      // exchange: give the other rt's partials, keep own
      xch[rgive][0][L] = h ? zp0[0] : zp0[1];
      xch[rgive][1][L] = h ? zp1[0] : zp1[1];
      __syncthreads();
      f32x4 z0 = (h ? zp0[1] : zp0[0]) + xch[rkeep][0][L];
      f32x4 z1 = (h ? zp1[1] : zp1[0]) + xch[rkeep][1][L];

      uint wd0, wd1;
      ACT(z0, __uint_as_float((uint)qa0), __uint_as_float((uint)(qa0 >> 32)),
          __uint_as_float((uint)qa1), __uint_as_float((uint)(qa1 >> 32)), c0, wd0);
      ACT(z1, __uint_as_float((uint)qb0), __uint_as_float((uint)(qb0 >> 32)),
          __uint_as_float((uint)qb1), __uint_as_float((uint)(qb1 >> 32)), c1, wd1);

      if (G < TT) {
        AT_ST(&seq[(size_t)G * HB + (size_t)j_own * BB + col0], wd0);
        AT_ST(&seq[(size_t)G * HB + (size_t)j_own * BB + col0 + 16], wd1);
        if (G == TT - 1) {        // seed h2(-1) into ring slot 3
          AT_ST(&ring[(size_t)3 * HB + (size_t)j_own * BB + col0], wd0);
          AT_ST(&ring[(size_t)3 * HB + (size_t)j_own * BB + col0 + 16], wd1);
        }
      } else {
        AT_ST(&ring[(size_t)(G & 3) * HB + (size_t)j_own * BB + col0], wd0);
        AT_ST(&ring[(size_t)(G & 3) * HB + (size_t)j_own * BB + col0 + 16], wd1);
      }
      __syncthreads();            // drain stores of all 4 waves + LDS reuse
      if (tid == 0) AT_ST(hflags + pidx, G + 1);
    }
  } else {
    // ---------------- PROJ block (K-split identical) ----------------
#pragma unroll
    for (int r = 0; r < 2; ++r)
#pragma unroll
      for (int kk = 0; kk < 2; ++kk) {
        const ushort* pp = W1pk + (((size_t)(rt0 + r) * 4 + (2 * h + kk)) * 64 + L) * 16;
        uh[r][kk] = *(const short8*)(pp); ul[r][kk] = *(const short8*)(pp + 8);
      }
    float4 bv = *(const float4*)(bp1 + j_own * 4);

#pragma unroll 1
    for (int G = 0; G < 2 * TT; ++G) {
      if (G == TT) {              // layer 2: W2 frags resident + bias
#pragma unroll
        for (int r = 0; r < 2; ++r)
#pragma unroll
          for (int kk = 0; kk < 8; ++kk) {
            const ushort* pp = W2pk + (((size_t)(rt0 + r) * 16 + (8 * h + kk)) * 64 + L) * 16;
            uh[r][kk] = *(const short8*)(pp); ul[r][kk] = *(const short8*)(pp + 8);
          }
        bv = *(const float4*)(bp2 + j_own * 4);
      }
      // throttle: slot G&7 last consumed by partner at G-8 -> hflag >= G-7
      if (G >= 8) {
        while (AT_LD(hflags + pidx) < G - 7) __builtin_amdgcn_s_sleep(1);
      }
      asm volatile("" ::: "memory");

      f32x4 zp0[2], zp1[2];
      if (G < TT) {
        // xz1 = W1 * x(G): this wave's 2 k-tiles (kt = 2h+kk)
#pragma unroll
        for (int r = 0; r < 2; ++r) {
          zp0[r] = (f32x4){0.f, 0.f, 0.f, 0.f}; zp1[r] = zp0[r];
        }
#define PROJA_CT(COLC, ZP) {                                             \
        f32x4 P0[2], P1[2], P2[2];                                       \
        _Pragma("unroll")                                                \
        for (int r = 0; r < 2; ++r) {                                    \
          P0[r] = (f32x4){0.f, 0.f, 0.f, 0.f}; P1[r] = P0[r]; P2[r] = P0[r]; \
        }                                                                \
        const float* xp = x + ((size_t)(COLC) * TT + G) * FF + q * 8 + 64 * h; \
        _Pragma("unroll")                                                \
        for (int kk = 0; kk < 2; ++kk) {                                 \
          float4 v0 = *(const float4*)(xp + kk * 32);                    \
          float4 v1 = *(const float4*)(xp + kk * 32 + 4);                \
          float xf[8] = {v0.x, v0.y, v0.z, v0.w, v1.x, v1.y, v1.z, v1.w}; \
          short8 xh, xl;                                                 \
          _Pragma("unroll")                                              \
          for (int u = 0; u < 8; ++u) {                                  \
            ushort hi = f2bf(xf[u]);                                     \
            xl[u] = (short)f2bf(xf[u] - bfh(hi));                        \
            xh[u] = (short)hi;                                           \
          }                                                              \
          _Pragma("unroll")                                              \
          for (int r = 0; r < 2; ++r) {                                  \
            P0[r] = MFMA(uh[r][kk], xh, P0[r], 0, 0, 0);                 \
            P1[r] = MFMA(ul[r][kk], xh, P1[r], 0, 0, 0);                 \
            P2[r] = MFMA(uh[r][kk], xl, P2[r], 0, 0, 0);                 \
          }                                                              \
        }                                                                \
        ZP[0] = P0[0] + P1[0] + P2[0];                                   \
        ZP[1] = P0[1] + P1[1] + P2[1];                                   \
      }
        PROJA_CT(col0, zp0);
        PROJA_CT(col0 + 16, zp1);
      } else {
        // xz2 = W2 * h1(sp): seq final -> plain loads
        int sp = G - TT;
        const uint* hs = seq + (size_t)sp * HB + (size_t)(256 * h) * BB;
        LOADMM(hs, PLD, col0, zp0);
        LOADMM(hs, PLD, col0 + 16, zp1);
      }
      // exchange + owner writes xz (+bias) to the 8-slot ring
      xch[rgive][0][L] = h ? zp0[0] : zp0[1];
      xch[rgive][1][L] = h ? zp1[0] : zp1[1];
      __syncthreads();
      f32x4 z0 = (h ? zp0[1] : zp0[0]) + xch[rkeep][0][L];
      f32x4 z1 = (h ? zp1[1] : zp1[0]) + xch[rkeep][1][L];
      {
        u64* dp = (u64*)(xzr + ((size_t)(G & 7) * HB + (size_t)j_own * BB + col0));
        AT_ST(dp, pk2f(z0.x + bv.x, z0.y + bv.y));
        AT_ST(dp + 1, pk2f(z0.z + bv.z, z0.w + bv.w));
        u64* dq = (u64*)(xzr + ((size_t)(G & 7) * HB + (size_t)j_own * BB + col0 + 16));
        AT_ST(dq, pk2f(z1.x + bv.x, z1.y + bv.y));
        AT_ST(dq + 1, pk2f(z1.z + bv.z, z1.w + bv.w));
      }
      __syncthreads();
      if (tid == 0) AT_ST(pflags + pidx, G + 1);
    }
  }
}

// ---------------- dense + softmax (reads ring slot 3 words) ----------------
__global__ __launch_bounds__(64) void k_dense(const uint* __restrict__ h2,
                                              const float* __restrict__ Wd,
                                              const float* __restrict__ bd,
                                              float* __restrict__ out) {
  int b = blockIdx.x * 64 + threadIdx.x;
  float acc[10];
#pragma unroll
  for (int c = 0; c < 10; ++c) acc[c] = bd[c];
  for (int k = 0; k < HH; ++k) {
    uint w = h2[k * BB + b];
    float hv = __uint_as_float(w & 0xffff0000u) + __uint_as_float(w << 16);
#pragma unroll
    for (int c = 0; c < 10; ++c) acc[c] = fmaf(hv, Wd[k * 10 + c], acc[c]);
  }
  float m = acc[0];
#pragma unroll
  for (int c = 1; c < 10; ++c) m = fmaxf(m, acc[c]);
  float s = 0.f;
#pragma unroll
  for (int c = 0; c < 10; ++c) { acc[c] = __expf(acc[c] - m); s += acc[c]; }
  float inv = 1.f / s;
#pragma unroll
  for (int c = 0; c < 10; ++c) out[b * 10 + c] = acc[c] * inv;
}

// ---------------- host ----------------
extern "C" void kernel_launch(void* const* d_in, const int* in_sizes, int n_in,
                              void* d_out, int out_size, void* d_ws, size_t ws_size,
                              hipStream_t stream) {
  const float* x  = (const float*)d_in[0];
  const float* W1 = (const float*)d_in[1];
  const float* U1 = (const float*)d_in[2];
  const float* b1 = (const float*)d_in[3];
  const float* W2 = (const float*)d_in[4];
  const float* U2 = (const float*)d_in[5];
  const float* b2 = (const float*)d_in[6];
  const float* Wd = (const float*)d_in[7];
  const float* bd = (const float*)d_in[8];
  float* out = (float*)d_out;

  // workspace layout (~157 MB, < proven 181 MB)
  uint*   seq   = (uint*)d_ws;                      // [512][HB]   128 MB
  uint*   ring  = seq + (size_t)TT * HB;            // [4][HB]       1 MB
  float4* xzr   = (float4*)(ring + (size_t)4 * HB); // [8][HB] f4    8 MB
  ushort* W1pk  = (ushort*)(xzr + (size_t)8 * HB);  //   524,288 ush
  ushort* U1pk  = W1pk + (size_t)524288;            // 2,097,152 ush
  ushort* U2pk  = U1pk + (size_t)2097152;           // 2,097,152 ush
  ushort* W2pk  = U2pk + (size_t)2097152;           // 2,097,152 ush
  float*  bp1   = (float*)(W2pk + (size_t)2097152); // 2,048 f
  float*  bp2   = bp1 + NR;                         // 2,048 f
  int*    hflags = (int*)(bp2 + NR);                // 128*FLS ints
  int*    pflags = hflags + 128 * FLS;              // 128*FLS ints

  k_zero<<<16, 256, 0, stream>>>((float*)hflags, 2 * 128 * FLS);
  k_rearr_b<<<8, 256, 0, stream>>>(b1, bp1);
  k_rearr_b<<<8, 256, 0, stream>>>(b2, bp2);
  k_pack_A<<<1024, 256, 0, stream>>>(W1, W1pk, 2);   // K=128 -> 4 k-tiles
  k_pack_A<<<4096, 256, 0, stream>>>(U1, U1pk, 4);   // K=512 -> 16 k-tiles
  k_pack_A<<<4096, 256, 0, stream>>>(U2, U2pk, 4);
  k_pack_A<<<4096, 256, 0, stream>>>(W2, W2pk, 4);

  k_fused<<<256, 256, 0, stream>>>(x, W1pk, U1pk, bp1, W2pk, U2pk, bp2,
                                   seq, ring, xzr, hflags, pflags);
  k_dense<<<2, 64, 0, stream>>>(ring + (size_t)3 * HB, Wd, bd, out);
}